// Round 7
// baseline (630.542 us; speedup 1.0000x reference)
//
#include <hip/hip_runtime.h>

typedef __attribute__((ext_vector_type(8))) short short8;
typedef __attribute__((ext_vector_type(4))) float floatx4;

__device__ __forceinline__ float b2f(unsigned int u) { return __uint_as_float(u << 16); }
__device__ __forceinline__ unsigned short f2b(float f) {      // fp32 -> bf16 RNE
    unsigned int u = __float_as_uint(f);
    return (unsigned short)((u + 0x7fffu + ((u >> 16) & 1u)) >> 16);
}
__device__ __forceinline__ unsigned cvtpk(float lo, float hi) {  // 2xf32 -> packed bf16 (RNE)
    unsigned r;
    asm("v_cvt_pk_bf16_f32 %0, %1, %2" : "=v"(r) : "v"(lo), "v"(hi));
    return r;
}

#define EMB 128
#define NN  500000
#define BB  1024
#define NCT 9        // 8 feat col-tiles + 1 gate tile (col 128 = w_mask)
#define CH  4        // 16-row tiles per wave (chunk)

// ---------------------------------------------------------------- init (+ inlined dtype detect)
// wTf fragment-major: wTf[((kk*NCT+ct)*64+lane)*8+j]
// = Blogical[n = ct*16 + (lane&15)][k = kk*32 + (lane>>4)*8 + j], where
// Blogical[n][k] = w_feat[k][n] (n<128), w_mask[k] (n==128), 0 else.
__global__ __launch_bounds__(256)
void kinit(float* __restrict__ denom, float* __restrict__ xg,
           unsigned short* __restrict__ wTf, const void* __restrict__ w_feat_,
           const void* __restrict__ w_mask_, const unsigned short* __restrict__ xr,
           const int* __restrict__ braw, int* __restrict__ flags, int N)
{
    __shared__ int sf32;
    int tid = threadIdx.x;
    if (tid < 64) {
        int good = 0;
#pragma unroll
        for (int j = 0; j < 4; ++j) {
            unsigned short u = xr[tid * 4 + j];
            unsigned e = (u >> 7) & 0xffu;
            if ((e >= 100u && e <= 140u) || u == 0) ++good;
        }
#pragma unroll
        for (int o = 1; o < 64; o <<= 1) good += __shfl_xor(good, o);
        if (tid == 0) {
            sf32 = (good < 240) ? 1 : 0;
            if (blockIdx.x == 0) {
                flags[0] = sf32;
                flags[1] = (braw[N - 1] == 0 && braw[N - 2] != 0) ? 1 : 0;
            }
        }
    }
    __syncthreads();
    bool f32 = sf32 != 0;

    int i = blockIdx.x * 256 + tid;
    if (i < BB) denom[i] = 0.f;
    if (i < BB * EMB) xg[i] = 0.f;
    if (i < 4 * NCT * 512) {
        int blk = i >> 9, rem = i & 511;
        int lane = rem >> 3, j = rem & 7;
        int kk = blk / NCT, ct = blk - kk * NCT;
        int n = ct * 16 + (lane & 15);
        int k = kk * 32 + (lane >> 4) * 8 + j;
        unsigned short v = 0;
        if (n < 128)      v = f32 ? f2b(((const float*)w_feat_)[k * EMB + n])
                                  : ((const unsigned short*)w_feat_)[k * EMB + n];
        else if (n == 128) v = f32 ? f2b(((const float*)w_mask_)[k])
                                   : ((const unsigned short*)w_mask_)[k];
        wTf[i] = v;
    }
}

// ---------------------------------------------------------------- per-tile compute (16 rows)
// MFMA 16x(128 feat + gate), shift-free softmax e, 16-elem segmented scan ->
// denom atomic, then register accumulation (racc) or boundary run-merge.
__device__ __forceinline__ void flush_racc(float (&racc)[8], int& runSeg,
                                           int quad, int l16, float* __restrict__ xg)
{
    if (runSeg >= 0) {
#pragma unroll
        for (int ct = 0; ct < 8; ++ct) {
            float p = racc[ct];
            p += __shfl_xor(p, 16);
            p += __shfl_xor(p, 32);
            if (quad == (ct & 3))
                atomicAdd(&xg[runSeg * EMB + ct * 16 + l16], p);
            racc[ct] = 0.f;
        }
    }
    runSeg = -1;
}

__device__ __forceinline__ void tile_compute(
    const short8 (&afr)[4], int sv, const unsigned short* __restrict__ lB,
    float bm, const float (&bfv)[8], float* __restrict__ sew,
    int lane, int quad, int l16,
    float* __restrict__ denom, float* __restrict__ xg,
    float (&racc)[8], int& runSeg)
{
    const short8* lBf = (const short8*)lB;
    floatx4 zero = {0.f, 0.f, 0.f, 0.f};
    floatx4 acc[NCT];
#pragma unroll
    for (int ct = 0; ct < NCT; ++ct) acc[ct] = zero;

#pragma unroll
    for (int kk = 0; kk < 4; ++kk)
#pragma unroll
        for (int ct = 0; ct < NCT; ++ct) {
            short8 bf = lBf[(kk * NCT + ct) * 64 + lane];
            acc[ct] = __builtin_amdgcn_mfma_f32_16x16x32_bf16(afr[kk], bf, acc[ct], 0, 0, 0);
        }

    // gate column (ct==8, col 128 lives in l16==0 lanes): row = quad*4 + r
    if (l16 == 0) {
#pragma unroll
        for (int r = 0; r < 4; ++r) sew[quad * 4 + r] = acc[8][r];
    }

    // all lanes: gate for row l16 (broadcast LDS read), e = exp(gate)
    float g = sew[l16] + bm;
    float ev = (sv >= 0) ? __expf(fminf(g, 60.f)) : 0.f;

    // 16-element segmented scan (lanes 0..15) -> one atomicAdd(denom) per run
    if (lane < 16) {
        float v = ev;
#pragma unroll
        for (int o = 1; o < 16; o <<= 1) {
            float u  = __shfl_up(v, o);
            int   su = __shfl_up(sv, o);
            if (lane >= o && su == sv) v += u;
        }
        int sn = __shfl_down(sv, 1);
        if (sv >= 0 && (lane == 15 || sn != sv)) atomicAdd(&denom[sv], v);
    }

    // e for this lane's 4 rows via shuffle (row quad*4+r lives at lane quad*4+r)
    float er[4];
#pragma unroll
    for (int r = 0; r < 4; ++r) er[r] = __shfl(ev, quad * 4 + r);

    int sF = __shfl(sv, 0), sL = __shfl(sv, 15);
    if (sF == sL) {
        if (sF >= 0) {
            if (sF != runSeg) { flush_racc(racc, runSeg, quad, l16, xg); runSeg = sF; }
#pragma unroll
            for (int ct = 0; ct < 8; ++ct) {
                float p = 0.f;
#pragma unroll
                for (int r = 0; r < 4; ++r) {
                    float v = acc[ct][r] + bfv[ct];
                    v = v >= 0.f ? v : 0.01f * v;
                    p += v * er[r];
                }
                racc[ct] += p;
            }
        }
    } else {
        flush_racc(racc, runSeg, quad, l16, xg);
        int sr[4];
#pragma unroll
        for (int r = 0; r < 4; ++r) sr[r] = __shfl(sv, quad * 4 + r);
#pragma unroll
        for (int ct = 0; ct < 8; ++ct) {
            int col = ct * 16 + l16;
            float a = 0.f; int cur = -1;
#pragma unroll
            for (int r = 0; r < 4; ++r) {
                int s = sr[r];
                float v = acc[ct][r] + bfv[ct];
                v = v >= 0.f ? v : 0.01f * v;
                v *= er[r];
                if (s != cur) {
                    if (cur >= 0) atomicAdd(&xg[cur * EMB + col], a);
                    a = 0.f; cur = s;
                }
                if (s >= 0) a += v;
            }
            if (cur >= 0) atomicAdd(&xg[cur * EMB + col], a);
        }
    }
}

// ---------------------------------------------------------------- pipelined fused main
// Each wave owns CH consecutive 16-row tiles. Register double-buffer (16-row
// tile = 32 f32 regs, so buf+buf+acc fits without spill): tile t+1's 8
// dwordx4 loads (+1 braw) are issued BEFORE tile t's convert/MFMA/epilogue,
// keeping global loads outstanding throughout. B (36 KB) staged once per
// block into LDS. One __syncthreads total.
__global__ __launch_bounds__(256, 3)
void kmain(const void* __restrict__ x_, const int* __restrict__ braw,
           const void* __restrict__ bm_, const void* __restrict__ bf_,
           const unsigned short* __restrict__ wTf, const int* __restrict__ flags,
           float* __restrict__ denom, float* __restrict__ xg, int N)
{
    __shared__ __align__(16) unsigned short lB[4 * NCT * 512];  // 36864 B
    __shared__ float se[4][16];

    int tid = threadIdx.x;
    int wave = tid >> 6, lane = tid & 63;
    int quad = lane >> 4, l16 = lane & 15;
    bool f32  = flags[0] != 0;
    bool is64 = flags[1] != 0;

    int T = (N + 15) >> 4;
    int W = blockIdx.x * 4 + wave;
    int t0 = W * CH;
    int tend = t0 + CH; if (tend > T) tend = T;

    float bm = f32 ? ((const float*)bm_)[0]
                   : b2f((unsigned int)((const unsigned short*)bm_)[0]);
    float bfv[8];
#pragma unroll
    for (int ct = 0; ct < 8; ++ct)
        bfv[ct] = f32 ? ((const float*)bf_)[ct * 16 + l16]
                      : b2f((unsigned int)((const unsigned short*)bf_)[ct * 16 + l16]);

    // ---- prologue A-loads (issued before B staging so they overlap it)
    float4 rA[8], rB[8];
    short8 hA[4], hB[4];
    int sA = -1, sB = -1;
    const float* xf = (const float*)x_;
    const unsigned short* xu = (const unsigned short*)x_;
    float4 fz = make_float4(0.f, 0.f, 0.f, 0.f);
    short8 hz = {0, 0, 0, 0, 0, 0, 0, 0};

#define SEGLD(sdst, tt) do {                                                    \
        int n_ = ((tt) << 4) + l16; int v_ = -1;                                \
        if (n_ < N) { int b_ = is64 ? braw[2 * n_] : braw[n_];                  \
                      if (b_ >= 0 && b_ < BB) v_ = b_; }                        \
        sdst = v_;                                                              \
    } while (0)

#define LOADF(dst, sdst, tt) do {                                               \
        SEGLD(sdst, tt);                                                        \
        int n_ = ((tt) << 4) + l16;                                             \
        const float* p_ = xf + (size_t)n_ * EMB + quad * 8;                     \
        _Pragma("unroll")                                                       \
        for (int kk = 0; kk < 4; ++kk) {                                        \
            dst[kk * 2]     = (n_ < N) ? *(const float4*)(p_ + kk * 32)     : fz; \
            dst[kk * 2 + 1] = (n_ < N) ? *(const float4*)(p_ + kk * 32 + 4) : fz; \
        }                                                                       \
    } while (0)

#define CONVF(afr, src) do {                                                    \
        _Pragma("unroll")                                                       \
        for (int kk = 0; kk < 4; ++kk) {                                        \
            float4 a_ = src[kk * 2], b_ = src[kk * 2 + 1];                      \
            union { short8 s; unsigned u[4]; } cv_;                             \
            cv_.u[0] = cvtpk(a_.x, a_.y); cv_.u[1] = cvtpk(a_.z, a_.w);         \
            cv_.u[2] = cvtpk(b_.x, b_.y); cv_.u[3] = cvtpk(b_.z, b_.w);         \
            afr[kk] = cv_.s;                                                    \
        }                                                                       \
    } while (0)

#define LOADH(dst, sdst, tt) do {                                               \
        SEGLD(sdst, tt);                                                        \
        int n_ = ((tt) << 4) + l16;                                             \
        const unsigned short* p_ = xu + (size_t)n_ * EMB + quad * 8;            \
        _Pragma("unroll")                                                       \
        for (int kk = 0; kk < 4; ++kk)                                          \
            dst[kk] = (n_ < N) ? *(const short8*)(p_ + kk * 32) : hz;           \
    } while (0)

    bool havew = t0 < tend;
    if (havew) { if (f32) LOADF(rA, sA, t0); else LOADH(hA, sA, t0); }

    // ---- stage wTf (36 KB) into LDS: coalesced uint4, conflict-free ds_write
    {
        const uint4* wg = (const uint4*)wTf;
        uint4* wl = (uint4*)lB;
        uint4 wv[9];
#pragma unroll
        for (int i = 0; i < 9; ++i) wv[i] = wg[i * 256 + tid];
#pragma unroll
        for (int i = 0; i < 9; ++i) wl[i * 256 + tid] = wv[i];
    }
    __syncthreads();
    if (!havew) return;

    float racc[8];
#pragma unroll
    for (int ct = 0; ct < 8; ++ct) racc[ct] = 0.f;
    int runSeg = -1;
    float* sew = se[wave];

    int t = t0;
    if (f32) {
        while (true) {
            {   // data in rA
                if (t + 1 < tend) LOADF(rB, sB, t + 1);
                short8 afr[4];
                CONVF(afr, rA);
                tile_compute(afr, sA, lB, bm, bfv, sew, lane, quad, l16,
                             denom, xg, racc, runSeg);
                ++t; if (t >= tend) break;
            }
            {   // data in rB
                if (t + 1 < tend) LOADF(rA, sA, t + 1);
                short8 afr[4];
                CONVF(afr, rB);
                tile_compute(afr, sB, lB, bm, bfv, sew, lane, quad, l16,
                             denom, xg, racc, runSeg);
                ++t; if (t >= tend) break;
            }
        }
    } else {
        while (true) {
            {
                if (t + 1 < tend) LOADH(hB, sB, t + 1);
                tile_compute(hA, sA, lB, bm, bfv, sew, lane, quad, l16,
                             denom, xg, racc, runSeg);
                ++t; if (t >= tend) break;
            }
            {
                if (t + 1 < tend) LOADH(hA, sA, t + 1);
                tile_compute(hB, sB, lB, bm, bfv, sew, lane, quad, l16,
                             denom, xg, racc, runSeg);
                ++t; if (t >= tend) break;
            }
        }
    }

    flush_racc(racc, runSeg, quad, l16, xg);
#undef SEGLD
#undef LOADF
#undef CONVF
#undef LOADH
}

// ---------------------------------------------------------------- final: normalize + linear + leaky + residual
__global__ __launch_bounds__(128)
void kfinal(const float* __restrict__ xg, const float* __restrict__ denom,
            const void* __restrict__ xg_old_, const void* __restrict__ w_tr_,
            const void* __restrict__ b_tr_, const int* __restrict__ flags,
            void* __restrict__ out_)
{
    __shared__ float cat[2 * EMB];
    int b = blockIdx.x, j = threadIdx.x;
    bool f32 = flags[0] != 0;

    float d = denom[b];
    float xgv = xg[b * EMB + j];
    xgv = (d > 0.f) ? xgv / d : 0.f;
    if (xgv != xgv) xgv = 700.0f;                 // sentinel: NaN escaped kmain
    cat[j] = xgv;
    float old = f32 ? ((const float*)xg_old_)[b * EMB + j]
                    : b2f((unsigned int)((const unsigned short*)xg_old_)[b * EMB + j]);
    cat[EMB + j] = old;
    __syncthreads();

    float acc = f32 ? ((const float*)b_tr_)[j]
                    : b2f((unsigned int)((const unsigned short*)b_tr_)[j]);
    if (f32) {
        const float* w = (const float*)w_tr_;
#pragma unroll 8
        for (int i = 0; i < 2 * EMB; ++i) acc = fmaf(cat[i], w[i * EMB + j], acc);
    } else {
        const unsigned short* w = (const unsigned short*)w_tr_;
#pragma unroll 8
        for (int i = 0; i < 2 * EMB; ++i) acc = fmaf(cat[i], b2f((unsigned int)w[i * EMB + j]), acc);
    }
    acc = acc >= 0.f ? acc : 0.01f * acc;
    acc += old;
    if (acc != acc) acc = 300.0f;                 // sentinel: NaN in kfinal inputs

    if (f32) ((float*)out_)[b * EMB + j] = acc;
    else     ((unsigned short*)out_)[b * EMB + j] = f2b(acc);
}

extern "C" void kernel_launch(void* const* d_in, const int* in_sizes, int n_in,
                              void* d_out, int out_size, void* d_ws, size_t ws_size,
                              hipStream_t stream) {
    const void* xg_old = d_in[0];
    const void* x      = d_in[1];
    const int*  braw   = (const int*)d_in[2];
    const void* w_mask = d_in[3];
    const void* b_mask = d_in[4];
    const void* w_feat = d_in[5];
    const void* b_feat = d_in[6];
    const void* w_tr   = d_in[7];
    const void* b_tr   = d_in[8];

    const int N = NN;

    char* ws = (char*)d_ws;
    size_t off = 0;
    int*   flags = (int*)(ws + off);   off += 64;
    float* denom = (float*)(ws + off); off += (size_t)BB * 4;
    float* xg    = (float*)(ws + off); off += (size_t)BB * EMB * 4;
    unsigned short* wTf = (unsigned short*)(ws + off); off += (size_t)4 * NCT * 512 * 2;

    int T = (N + 15) >> 4;
    int nblk = (T + 4 * CH - 1) / (4 * CH);
    kinit<<<(BB * EMB + 255) / 256, 256, 0, stream>>>(denom, xg, wTf, w_feat, w_mask,
                                                      (const unsigned short*)x, braw, flags, N);
    kmain<<<nblk, 256, 0, stream>>>(x, braw, b_mask, b_feat, wTf,
                                    flags, denom, xg, N);
    kfinal<<<BB, 128, 0, stream>>>(xg, denom, xg_old, w_tr, b_tr, flags, d_out);
}

// Round 8
// 397.283 us; speedup vs baseline: 1.5871x; 1.5871x over previous
//
#include <hip/hip_runtime.h>

typedef __attribute__((ext_vector_type(8))) short short8;
typedef __attribute__((ext_vector_type(4))) float floatx4;

__device__ __forceinline__ float b2f(unsigned int u) { return __uint_as_float(u << 16); }
__device__ __forceinline__ unsigned short f2b(float f) {      // fp32 -> bf16 RNE
    unsigned int u = __float_as_uint(f);
    return (unsigned short)((u + 0x7fffu + ((u >> 16) & 1u)) >> 16);
}
__device__ __forceinline__ unsigned cvtpk(float lo, float hi) {  // 2xf32 -> packed bf16 (RNE)
    unsigned r;
    asm("v_cvt_pk_bf16_f32 %0, %1, %2" : "=v"(r) : "v"(lo), "v"(hi));
    return r;
}
// async global->LDS DMA: 64 lanes x 16B; LDS dst = wave-uniform base + lane*16,
// global src is PER-LANE (pre-swizzled source, linear LDS -- m173 pattern).
__device__ __forceinline__ void dma16(const void* gsrc, void* ldst) {
    __builtin_amdgcn_global_load_lds(
        (const __attribute__((address_space(1))) void*)gsrc,
        (__attribute__((address_space(3))) void*)ldst, 16, 0, 0);
}

#define EMB 128
#define NN  500000
#define BB  1024
#define NCT 9        // 8 feat col-tiles + 1 gate tile (col 128 = w_mask)
#define CH  16       // 16-row tiles per wave chunk
#define WTB (4 * NCT * 512)   // wTf elements

// ---------------------------------------------------------------- init (+ inlined dtype detect)
__global__ __launch_bounds__(256)
void kinit(float* __restrict__ denom, float* __restrict__ xg,
           unsigned short* __restrict__ wTf, const void* __restrict__ w_feat_,
           const void* __restrict__ w_mask_, const unsigned short* __restrict__ xr,
           const int* __restrict__ braw, int* __restrict__ flags, int N)
{
    __shared__ int sf32;
    int tid = threadIdx.x;
    if (tid < 64) {
        int good = 0;
#pragma unroll
        for (int j = 0; j < 4; ++j) {
            unsigned short u = xr[tid * 4 + j];
            unsigned e = (u >> 7) & 0xffu;
            if ((e >= 100u && e <= 140u) || u == 0) ++good;
        }
#pragma unroll
        for (int o = 1; o < 64; o <<= 1) good += __shfl_xor(good, o);
        if (tid == 0) {
            sf32 = (good < 240) ? 1 : 0;
            if (blockIdx.x == 0) {
                flags[0] = sf32;
                flags[1] = (braw[N - 1] == 0 && braw[N - 2] != 0) ? 1 : 0;
            }
        }
    }
    __syncthreads();
    bool f32 = sf32 != 0;

    int i = blockIdx.x * 256 + tid;
    if (i < BB) denom[i] = 0.f;
    if (i < BB * EMB) xg[i] = 0.f;
    if (i < WTB) {
        int blk = i >> 9, rem = i & 511;
        int lane = rem >> 3, j = rem & 7;
        int kk = blk / NCT, ct = blk - kk * NCT;
        int n = ct * 16 + (lane & 15);
        int k = kk * 32 + (lane >> 4) * 8 + j;
        unsigned short v = 0;
        if (n < 128)      v = f32 ? f2b(((const float*)w_feat_)[k * EMB + n])
                                  : ((const unsigned short*)w_feat_)[k * EMB + n];
        else if (n == 128) v = f32 ? f2b(((const float*)w_mask_)[k])
                                   : ((const unsigned short*)w_mask_)[k];
        wTf[i] = v;
    }
}

// ---------------------------------------------------------------- per-tile compute (16 rows)
__device__ __forceinline__ void flush_racc(float (&racc)[8], int& runSeg,
                                           int quad, int l16, float* __restrict__ xg)
{
    if (runSeg >= 0) {
#pragma unroll
        for (int ct = 0; ct < 8; ++ct) {
            float p = racc[ct];
            p += __shfl_xor(p, 16);
            p += __shfl_xor(p, 32);
            if (quad == (ct & 3))
                atomicAdd(&xg[runSeg * EMB + ct * 16 + l16], p);
            racc[ct] = 0.f;
        }
    }
    runSeg = -1;
}

__device__ __forceinline__ void tile_compute(
    const short8 (&afr)[4], int sv, const unsigned short* __restrict__ lB,
    float bm, const float (&bfv)[8], float* __restrict__ sew,
    int lane, int quad, int l16,
    float* __restrict__ denom, float* __restrict__ xg,
    float (&racc)[8], int& runSeg)
{
    const short8* lBf = (const short8*)lB;
    floatx4 zero = {0.f, 0.f, 0.f, 0.f};
    floatx4 acc[NCT];
#pragma unroll
    for (int ct = 0; ct < NCT; ++ct) acc[ct] = zero;

#pragma unroll
    for (int kk = 0; kk < 4; ++kk)
#pragma unroll
        for (int ct = 0; ct < NCT; ++ct) {
            short8 bf = lBf[(kk * NCT + ct) * 64 + lane];
            acc[ct] = __builtin_amdgcn_mfma_f32_16x16x32_bf16(afr[kk], bf, acc[ct], 0, 0, 0);
        }

    // gate column (ct==8, col 128 lives in l16==0 lanes): row = quad*4 + r
    if (l16 == 0) {
#pragma unroll
        for (int r = 0; r < 4; ++r) sew[quad * 4 + r] = acc[8][r];
    }

    float g = sew[l16] + bm;
    float ev = (sv >= 0) ? __expf(fminf(g, 60.f)) : 0.f;

    // 16-element segmented scan (lanes 0..15) -> one atomicAdd(denom) per run
    if (lane < 16) {
        float v = ev;
#pragma unroll
        for (int o = 1; o < 16; o <<= 1) {
            float u  = __shfl_up(v, o);
            int   su = __shfl_up(sv, o);
            if (lane >= o && su == sv) v += u;
        }
        int sn = __shfl_down(sv, 1);
        if (sv >= 0 && (lane == 15 || sn != sv)) atomicAdd(&denom[sv], v);
    }

    float er[4];
#pragma unroll
    for (int r = 0; r < 4; ++r) er[r] = __shfl(ev, quad * 4 + r);

    int sF = __shfl(sv, 0), sL = __shfl(sv, 15);
    if (sF == sL) {
        if (sF >= 0) {
            if (sF != runSeg) { flush_racc(racc, runSeg, quad, l16, xg); runSeg = sF; }
#pragma unroll
            for (int ct = 0; ct < 8; ++ct) {
                float p = 0.f;
#pragma unroll
                for (int r = 0; r < 4; ++r) {
                    float v = acc[ct][r] + bfv[ct];
                    v = v >= 0.f ? v : 0.01f * v;
                    p += v * er[r];
                }
                racc[ct] += p;
            }
        }
    } else {
        flush_racc(racc, runSeg, quad, l16, xg);
        int sr[4];
#pragma unroll
        for (int r = 0; r < 4; ++r) sr[r] = __shfl(sv, quad * 4 + r);
#pragma unroll
        for (int ct = 0; ct < 8; ++ct) {
            int col = ct * 16 + l16;
            float a = 0.f; int cur = -1;
#pragma unroll
            for (int r = 0; r < 4; ++r) {
                int s = sr[r];
                float v = acc[ct][r] + bfv[ct];
                v = v >= 0.f ? v : 0.01f * v;
                v *= er[r];
                if (s != cur) {
                    if (cur >= 0) atomicAdd(&xg[cur * EMB + col], a);
                    a = 0.f; cur = s;
                }
                if (s >= 0) a += v;
            }
            if (cur >= 0) atomicAdd(&xg[cur * EMB + col], a);
        }
    }
}

// ---------------------------------------------------------------- DMA-pipelined fused main
// Each wave owns CH consecutive 16-row tiles with a 2x8KB LDS double-buffer
// filled by global_load_lds (zero VGPR cost -> no spill possible). Counted
// s_waitcnt vmcnt(8) keeps the next tile's 8 DMAs in flight across the whole
// compute phase; vmcnt is never drained to 0 except the last two iterations.
// wTf (36KB) staged once per block. 1 block/CU (LDS-bound) BY DESIGN:
// latency hiding comes from DMA depth, not TLP.
__global__ __launch_bounds__(256)
void kmain(const void* __restrict__ x_, const int* __restrict__ braw,
           const void* __restrict__ bm_, const void* __restrict__ bf_,
           const unsigned short* __restrict__ wTf, const int* __restrict__ flags,
           float* __restrict__ denom, float* __restrict__ xg, int N)
{
    __shared__ __align__(16) char smem[WTB * 2 + 4 * 16384];  // 36864 + 65536
    __shared__ float se[4][16];
    unsigned short* lB = (unsigned short*)smem;               // wTf copy

    int tid = threadIdx.x;
    int wave = tid >> 6, lane = tid & 63;
    int quad = lane >> 4, l16 = lane & 15;
    bool f32  = flags[0] != 0;
    bool is64 = flags[1] != 0;

    int T = (N + 15) >> 4;
    int W = blockIdx.x * 4 + wave;
    int t0 = W * CH;
    int tend = t0 + CH; if (tend > T) tend = T;

    // ---- stage wTf into LDS (coalesced, conflict-free)
    {
        const uint4* wg = (const uint4*)wTf;
        uint4* wl = (uint4*)lB;
        uint4 wv[9];
#pragma unroll
        for (int i = 0; i < 9; ++i) wv[i] = wg[i * 256 + tid];
#pragma unroll
        for (int i = 0; i < 9; ++i) wl[i * 256 + tid] = wv[i];
    }
    __syncthreads();
    if (t0 >= tend) return;

    char* xbase = smem + WTB * 2 + wave * 16384;   // this wave's 2 buffers
    const char* xb = (const char*)x_;

    float bm = f32 ? ((const float*)bm_)[0]
                   : b2f((unsigned int)((const unsigned short*)bm_)[0]);
    float bfv[8];
#pragma unroll
    for (int ct = 0; ct < 8; ++ct)
        bfv[ct] = f32 ? ((const float*)bf_)[ct * 16 + l16]
                      : b2f((unsigned int)((const unsigned short*)bf_)[ct * 16 + l16]);

    // ---- DMA issue for one tile (pre-swizzled source, linear LDS dest)
#define DMAF(tt, bufp) do {                                                     \
        int rb_ = (tt) << 4;                                                    \
        _Pragma("unroll")                                                       \
        for (int j = 0; j < 8; ++j) {                                           \
            int r_ = 2 * j + (lane >> 5);                                       \
            unsigned c_ = (unsigned)(((lane & 31) << 4) ^ ((r_ & 7) << 4));     \
            dma16(xb + (((size_t)(rb_ + r_)) << 9) + c_, (bufp) + (j << 10));   \
        }                                                                       \
    } while (0)

#define DMAH(tt, bufp) do {                                                     \
        int rb_ = (tt) << 4;                                                    \
        _Pragma("unroll")                                                       \
        for (int j = 0; j < 4; ++j) {                                           \
            int r_ = 4 * j + (lane >> 4);                                       \
            unsigned c_ = (unsigned)(((lane & 15) << 4) ^ ((r_ & 7) << 4));     \
            dma16(xb + (((size_t)(rb_ + r_)) << 8) + c_, (bufp) + (j << 10));   \
        }                                                                       \
    } while (0)

    // prologue: fill the pipeline 2 deep
    if (f32) {
        DMAF(t0, xbase);
        if (t0 + 1 < tend) DMAF(t0 + 1, xbase + 8192);
    } else {
        DMAH(t0, xbase);
        if (t0 + 1 < tend) DMAH(t0 + 1, xbase + 8192);
    }

    float racc[8];
#pragma unroll
    for (int ct = 0; ct < 8; ++ct) racc[ct] = 0.f;
    int runSeg = -1;
    float* sew = se[wave];

    for (int t = t0; t < tend; ++t) {
        char* bufp = xbase + ((t & 1) << 13);

        // 1. arrival wait: counted vmcnt (tile t's DMAs are >= 9 ops older
        //    than the newest 8 in steady state); drain fully on the tail.
        if (t >= tend - 2) { asm volatile("s_waitcnt vmcnt(0)" ::: "memory"); }
        else if (f32)      { asm volatile("s_waitcnt vmcnt(8)" ::: "memory"); }
        else               { asm volatile("s_waitcnt vmcnt(4)" ::: "memory"); }
        __builtin_amdgcn_sched_barrier(0);

        // 2. segment id for row l16 of this tile (hidden under ds_reads/MFMA)
        int n_ = (t << 4) + l16;
        int sv = -1;
        if (n_ < N) { int b_ = is64 ? braw[2 * n_] : braw[n_]; if (b_ >= 0 && b_ < BB) sv = b_; }

        // 3. A-fragments from LDS (swizzled, bank-balanced b128 reads)
        short8 afr[4];
        if (f32) {
            float4 av[8];
#pragma unroll
            for (int kk = 0; kk < 4; ++kk)
#pragma unroll
                for (int h = 0; h < 2; ++h) {
                    unsigned off = (unsigned)(l16 << 9)
                                 + (unsigned)((((kk << 7) + (quad << 5) + (h << 4)) ^ ((l16 & 7) << 4)));
                    av[kk * 2 + h] = *(const float4*)(bufp + off);
                }
#pragma unroll
            for (int kk = 0; kk < 4; ++kk) {
                float4 a = av[kk * 2], b = av[kk * 2 + 1];
                union { short8 s; unsigned u[4]; } cv;
                cv.u[0] = cvtpk(a.x, a.y); cv.u[1] = cvtpk(a.z, a.w);
                cv.u[2] = cvtpk(b.x, b.y); cv.u[3] = cvtpk(b.z, b.w);
                afr[kk] = cv.s;
            }
        } else {
#pragma unroll
            for (int kk = 0; kk < 4; ++kk) {
                unsigned off = (unsigned)(l16 << 8)
                             + (unsigned)((((kk << 6) + (quad << 4)) ^ ((l16 & 7) << 4)));
                afr[kk] = *(const short8*)(bufp + off);
            }
        }

        // 4. reads retired before the buffer is overwritten
        asm volatile("s_waitcnt lgkmcnt(0)" ::: "memory");
        __builtin_amdgcn_sched_barrier(0);

        // 5. prefetch tile t+2 into the buffer just freed
        if (t + 2 < tend) {
            if (f32) DMAF(t + 2, bufp);
            else     DMAH(t + 2, bufp);
        }

        // 6. MFMA + gate + scan + weighted reduce (atomics fire-and-forget)
        tile_compute(afr, sv, lB, bm, bfv, sew, lane, quad, l16,
                     denom, xg, racc, runSeg);
    }

    flush_racc(racc, runSeg, quad, l16, xg);
#undef DMAF
#undef DMAH
}

// ---------------------------------------------------------------- final: normalize + linear + leaky + residual
__global__ __launch_bounds__(128)
void kfinal(const float* __restrict__ xg, const float* __restrict__ denom,
            const void* __restrict__ xg_old_, const void* __restrict__ w_tr_,
            const void* __restrict__ b_tr_, const int* __restrict__ flags,
            void* __restrict__ out_)
{
    __shared__ float cat[2 * EMB];
    int b = blockIdx.x, j = threadIdx.x;
    bool f32 = flags[0] != 0;

    float d = denom[b];
    float xgv = xg[b * EMB + j];
    xgv = (d > 0.f) ? xgv / d : 0.f;
    if (xgv != xgv) xgv = 700.0f;                 // sentinel: NaN escaped kmain
    cat[j] = xgv;
    float old = f32 ? ((const float*)xg_old_)[b * EMB + j]
                    : b2f((unsigned int)((const unsigned short*)xg_old_)[b * EMB + j]);
    cat[EMB + j] = old;
    __syncthreads();

    float acc = f32 ? ((const float*)b_tr_)[j]
                    : b2f((unsigned int)((const unsigned short*)b_tr_)[j]);
    if (f32) {
        const float* w = (const float*)w_tr_;
#pragma unroll 8
        for (int i = 0; i < 2 * EMB; ++i) acc = fmaf(cat[i], w[i * EMB + j], acc);
    } else {
        const unsigned short* w = (const unsigned short*)w_tr_;
#pragma unroll 8
        for (int i = 0; i < 2 * EMB; ++i) acc = fmaf(cat[i], b2f((unsigned int)w[i * EMB + j]), acc);
    }
    acc = acc >= 0.f ? acc : 0.01f * acc;
    acc += old;
    if (acc != acc) acc = 300.0f;                 // sentinel: NaN in kfinal inputs

    if (f32) ((float*)out_)[b * EMB + j] = acc;
    else     ((unsigned short*)out_)[b * EMB + j] = f2b(acc);
}

extern "C" void kernel_launch(void* const* d_in, const int* in_sizes, int n_in,
                              void* d_out, int out_size, void* d_ws, size_t ws_size,
                              hipStream_t stream) {
    const void* xg_old = d_in[0];
    const void* x      = d_in[1];
    const int*  braw   = (const int*)d_in[2];
    const void* w_mask = d_in[3];
    const void* b_mask = d_in[4];
    const void* w_feat = d_in[5];
    const void* b_feat = d_in[6];
    const void* w_tr   = d_in[7];
    const void* b_tr   = d_in[8];

    const int N = NN;

    char* ws = (char*)d_ws;
    size_t off = 0;
    int*   flags = (int*)(ws + off);   off += 64;
    float* denom = (float*)(ws + off); off += (size_t)BB * 4;
    float* xg    = (float*)(ws + off); off += (size_t)BB * EMB * 4;
    unsigned short* wTf = (unsigned short*)(ws + off); off += (size_t)WTB * 2;

    int T = (N + 15) >> 4;
    int nblk = (T + 4 * CH - 1) / (4 * CH);   // 489
    kinit<<<(BB * EMB + 255) / 256, 256, 0, stream>>>(denom, xg, wTf, w_feat, w_mask,
                                                      (const unsigned short*)x, braw, flags, N);
    kmain<<<nblk, 256, 0, stream>>>(x, braw, b_mask, b_feat, wTf,
                                    flags, denom, xg, N);
    kfinal<<<BB, 128, 0, stream>>>(xg, denom, xg_old, w_tr, b_tr, flags, d_out);
}